// Round 1
// baseline (909.461 us; speedup 1.0000x reference)
//
#include <hip/hip_runtime.h>
#include <hip/hip_bf16.h>

#define M_TOK 4096
#define K_DIM 4096
#define N_OUT 14336

typedef float f32x4 __attribute__((ext_vector_type(4)));
typedef short bf16x8 __attribute__((ext_vector_type(8)));
typedef unsigned short u16;
typedef unsigned int u32;
typedef u16 u16x8 __attribute__((ext_vector_type(8)));

__device__ __forceinline__ u16 f2bf_rne(float f) {
    u32 u = __builtin_bit_cast(u32, f);
    u += 0x7fffu + ((u >> 16) & 1u);
    return (u16)(u >> 16);
}

__device__ __forceinline__ void async16(const void* g, void* l) {
    __builtin_amdgcn_global_load_lds(
        (const __attribute__((address_space(1))) void*)g,
        (__attribute__((address_space(3))) void*)l, 16, 0, 0);
}

// ---------------- conversion kernels (two-pass path) ----------------

__global__ __launch_bounds__(256) void cvt_state_kernel(const float* __restrict__ src,
                                                        u16* __restrict__ dst) {
    size_t i = ((size_t)blockIdx.x * 256 + threadIdx.x) * 8;
    f32x4 v0 = *(const f32x4*)(src + i);
    f32x4 v1 = *(const f32x4*)(src + i + 4);
    u16x8 h;
    h[0] = f2bf_rne(v0[0]); h[1] = f2bf_rne(v0[1]);
    h[2] = f2bf_rne(v0[2]); h[3] = f2bf_rne(v0[3]);
    h[4] = f2bf_rne(v1[0]); h[5] = f2bf_rne(v1[1]);
    h[6] = f2bf_rne(v1[2]); h[7] = f2bf_rne(v1[3]);
    *(u16x8*)(dst + i) = h;
}

__global__ __launch_bounds__(256) void cvt_w_kernel(const float* __restrict__ w,
                                                    const int* __restrict__ eid,
                                                    u16* __restrict__ dst) {
    const float* src = w + (size_t)(*eid) * ((size_t)N_OUT * K_DIM);
    size_t i = ((size_t)blockIdx.x * 256 + threadIdx.x) * 8;
    f32x4 v0 = *(const f32x4*)(src + i);
    f32x4 v1 = *(const f32x4*)(src + i + 4);
    u16x8 h;
    h[0] = f2bf_rne(v0[0]); h[1] = f2bf_rne(v0[1]);
    h[2] = f2bf_rne(v0[2]); h[3] = f2bf_rne(v0[3]);
    h[4] = f2bf_rne(v1[0]); h[5] = f2bf_rne(v1[1]);
    h[6] = f2bf_rne(v1[2]); h[7] = f2bf_rne(v1[3]);
    *(u16x8*)(dst + i) = h;
}

// ---------------- bf16 GEMM, m97 structure ----------------
// C[M,N] = A[M,K] * B[N,K]^T, 128x128 tile, BK=32, 4 waves (2x2 of 64x64).
// LDS layout per tile: 8 groups x (4 kchunks x 16 rows x 16B) = 8KB, so a
// wave's fragment read is a contiguous ds_read_b128 at base + lane*16
// (conflict-free). global_load_lds dest is linear (l*16); the global source
// address realizes the permutation (m173 pattern).

__global__ __launch_bounds__(256) void gemm_bf16(const u16* __restrict__ A,
                                                 const u16* __restrict__ B,
                                                 float* __restrict__ C) {
    __shared__ __align__(16) u16 As[2][4096];
    __shared__ __align__(16) u16 Bs[2][4096];

    const int tid  = threadIdx.x;
    const int wid  = tid >> 6;
    const int lane = tid & 63;
    const int brow = blockIdx.y * 128;
    const int bcol = blockIdx.x * 128;
    const int wr = wid >> 1, wc = wid & 1;

    // staging source offsets (element index, this thread's 2 loads per matrix)
    const int l0 = tid, l1 = tid + 256;
    const size_t aoff0 = (size_t)(brow + ((l0 >> 6) * 16) + (l0 & 15)) * K_DIM + ((l0 >> 4) & 3) * 8;
    const size_t aoff1 = (size_t)(brow + ((l1 >> 6) * 16) + (l1 & 15)) * K_DIM + ((l1 >> 4) & 3) * 8;
    const size_t boff0 = (size_t)(bcol + ((l0 >> 6) * 16) + (l0 & 15)) * K_DIM + ((l0 >> 4) & 3) * 8;
    const size_t boff1 = (size_t)(bcol + ((l1 >> 6) * 16) + (l1 & 15)) * K_DIM + ((l1 >> 4) & 3) * 8;

    f32x4 acc[4][4] = {};

    auto stage = [&](int buf, int kt) {
        const int kk = kt * 32;
        async16(A + aoff0 + kk, &As[buf][(wid * 64) * 8]);
        async16(A + aoff1 + kk, &As[buf][(wid * 64 + 256) * 8]);
        async16(B + boff0 + kk, &Bs[buf][(wid * 64) * 8]);
        async16(B + boff1 + kk, &Bs[buf][(wid * 64 + 256) * 8]);
    };

    auto compute = [&](int buf) {
        bf16x8 a[4], b[4];
#pragma unroll
        for (int m = 0; m < 4; ++m)
            a[m] = *(const bf16x8*)&As[buf][(wr * 4 + m) * 512 + lane * 8];
#pragma unroll
        for (int n = 0; n < 4; ++n)
            b[n] = *(const bf16x8*)&Bs[buf][(wc * 4 + n) * 512 + lane * 8];
#pragma unroll
        for (int m = 0; m < 4; ++m)
#pragma unroll
            for (int n = 0; n < 4; ++n)
                acc[m][n] = __builtin_amdgcn_mfma_f32_16x16x32_bf16(a[m], b[n], acc[m][n], 0, 0, 0);
    };

    stage(0, 0);
    __syncthreads();
    int cur = 0;
#pragma unroll 1
    for (int kt = 0; kt < (K_DIM / 32) - 1; ++kt) {
        stage(cur ^ 1, kt + 1);
        compute(cur);
        __syncthreads();
        cur ^= 1;
    }
    compute(cur);

    // epilogue: D col = lane&15, row = (lane>>4)*4 + reg (m89-verified)
    const int r0 = (lane >> 4) * 4;
    const int cn = lane & 15;
#pragma unroll
    for (int m = 0; m < 4; ++m)
#pragma unroll
        for (int n = 0; n < 4; ++n) {
            float* cp = C + (size_t)(brow + wr * 64 + m * 16 + r0) * N_OUT
                          + (bcol + wc * 64 + n * 16 + cn);
#pragma unroll
            for (int j = 0; j < 4; ++j)
                cp[(size_t)j * N_OUT] = acc[m][n][j];
        }
}

// ---------------- fused-conversion fallback (no workspace) ----------------

__global__ __launch_bounds__(256) void gemm_fused(const float* __restrict__ Af,
                                                  const float* __restrict__ Wf,
                                                  const int* __restrict__ eid,
                                                  float* __restrict__ C) {
    const float* Bf = Wf + (size_t)(*eid) * ((size_t)N_OUT * K_DIM);

    __shared__ __align__(16) u16 As[2][4096];
    __shared__ __align__(16) u16 Bs[2][4096];

    const int tid  = threadIdx.x;
    const int wid  = tid >> 6;
    const int lane = tid & 63;
    const int brow = blockIdx.y * 128;
    const int bcol = blockIdx.x * 128;
    const int wr = wid >> 1, wc = wid & 1;

    f32x4 acc[4][4] = {};

    auto stage = [&](int buf, int kt) {
#pragma unroll
        for (int i = 0; i < 2; ++i) {
            const int l = tid + i * 256;
            const int g = l >> 6, c4 = (l >> 4) & 3, r = l & 15;
            {
                const size_t base = (size_t)(brow + g * 16 + r) * K_DIM + c4 * 8 + kt * 32;
                f32x4 v0 = *(const f32x4*)(Af + base);
                f32x4 v1 = *(const f32x4*)(Af + base + 4);
                u16x8 h;
                h[0] = f2bf_rne(v0[0]); h[1] = f2bf_rne(v0[1]);
                h[2] = f2bf_rne(v0[2]); h[3] = f2bf_rne(v0[3]);
                h[4] = f2bf_rne(v1[0]); h[5] = f2bf_rne(v1[1]);
                h[6] = f2bf_rne(v1[2]); h[7] = f2bf_rne(v1[3]);
                *(u16x8*)&As[buf][l * 8] = h;
            }
            {
                const size_t base = (size_t)(bcol + g * 16 + r) * K_DIM + c4 * 8 + kt * 32;
                f32x4 v0 = *(const f32x4*)(Bf + base);
                f32x4 v1 = *(const f32x4*)(Bf + base + 4);
                u16x8 h;
                h[0] = f2bf_rne(v0[0]); h[1] = f2bf_rne(v0[1]);
                h[2] = f2bf_rne(v0[2]); h[3] = f2bf_rne(v0[3]);
                h[4] = f2bf_rne(v1[0]); h[5] = f2bf_rne(v1[1]);
                h[6] = f2bf_rne(v1[2]); h[7] = f2bf_rne(v1[3]);
                *(u16x8*)&Bs[buf][l * 8] = h;
            }
        }
    };

    auto compute = [&](int buf) {
        bf16x8 a[4], b[4];
#pragma unroll
        for (int m = 0; m < 4; ++m)
            a[m] = *(const bf16x8*)&As[buf][(wr * 4 + m) * 512 + lane * 8];
#pragma unroll
        for (int n = 0; n < 4; ++n)
            b[n] = *(const bf16x8*)&Bs[buf][(wc * 4 + n) * 512 + lane * 8];
#pragma unroll
        for (int m = 0; m < 4; ++m)
#pragma unroll
            for (int n = 0; n < 4; ++n)
                acc[m][n] = __builtin_amdgcn_mfma_f32_16x16x32_bf16(a[m], b[n], acc[m][n], 0, 0, 0);
    };

    stage(0, 0);
    __syncthreads();
    int cur = 0;
#pragma unroll 1
    for (int kt = 0; kt < (K_DIM / 32) - 1; ++kt) {
        stage(cur ^ 1, kt + 1);
        compute(cur);
        __syncthreads();
        cur ^= 1;
    }
    compute(cur);

    const int r0 = (lane >> 4) * 4;
    const int cn = lane & 15;
#pragma unroll
    for (int m = 0; m < 4; ++m)
#pragma unroll
        for (int n = 0; n < 4; ++n) {
            float* cp = C + (size_t)(brow + wr * 64 + m * 16 + r0) * N_OUT
                          + (bcol + wc * 64 + n * 16 + cn);
#pragma unroll
            for (int j = 0; j < 4; ++j)
                cp[(size_t)j * N_OUT] = acc[m][n][j];
        }
}

// ---------------- launch ----------------

extern "C" void kernel_launch(void* const* d_in, const int* in_sizes, int n_in,
                              void* d_out, int out_size, void* d_ws, size_t ws_size,
                              hipStream_t stream) {
    const float* state = (const float*)d_in[0];
    const float* w     = (const float*)d_in[1];
    const int*   eid   = (const int*)d_in[2];
    float*       out   = (float*)d_out;

    const size_t nA = (size_t)M_TOK * K_DIM;   // 16,777,216
    const size_t nB = (size_t)N_OUT * K_DIM;   // 58,720,256
    const size_t need = (nA + nB) * sizeof(u16);

    dim3 grid(N_OUT / 128, M_TOK / 128);

    if (d_ws != nullptr && ws_size >= need) {
        u16* a16 = (u16*)d_ws;
        u16* b16 = a16 + nA;
        cvt_state_kernel<<<(unsigned)(nA / 2048), 256, 0, stream>>>(state, a16);
        cvt_w_kernel<<<(unsigned)(nB / 2048), 256, 0, stream>>>(w, eid, b16);
        gemm_bf16<<<grid, 256, 0, stream>>>(a16, b16, out);
    } else {
        gemm_fused<<<grid, 256, 0, stream>>>(state, w, eid, out);
    }
}

// Round 2
// 503.223 us; speedup vs baseline: 1.8073x; 1.8073x over previous
//
#include <hip/hip_runtime.h>
#include <hip/hip_bf16.h>

#define M_TOK 4096
#define K_DIM 4096
#define N_OUT 14336
#define NT (K_DIM / 64)   // 64 K-tiles of BK=64

typedef float f32x4 __attribute__((ext_vector_type(4)));
typedef short bf16x8 __attribute__((ext_vector_type(8)));
typedef unsigned short u16;
typedef unsigned int u32;
typedef u16 u16x8 __attribute__((ext_vector_type(8)));

__device__ __forceinline__ u16 f2bf_rne(float f) {
    u32 u = __builtin_bit_cast(u32, f);
    u += 0x7fffu + ((u >> 16) & 1u);
    return (u16)(u >> 16);
}

__device__ __forceinline__ void async16(const void* g, void* l) {
    __builtin_amdgcn_global_load_lds(
        (const __attribute__((address_space(1))) void*)g,
        (__attribute__((address_space(3))) void*)l, 16, 0, 0);
}

__device__ __forceinline__ void bar() {
    asm volatile("" ::: "memory");
    __builtin_amdgcn_s_barrier();
    asm volatile("" ::: "memory");
}

#define VMCNT(n) asm volatile("s_waitcnt vmcnt(" #n ")" ::: "memory")

// ---------------- conversion kernels ----------------

__global__ __launch_bounds__(256) void cvt_state_kernel(const float* __restrict__ src,
                                                        u16* __restrict__ dst) {
    size_t i = ((size_t)blockIdx.x * 256 + threadIdx.x) * 8;
    f32x4 v0 = *(const f32x4*)(src + i);
    f32x4 v1 = *(const f32x4*)(src + i + 4);
    u16x8 h;
    h[0] = f2bf_rne(v0[0]); h[1] = f2bf_rne(v0[1]);
    h[2] = f2bf_rne(v0[2]); h[3] = f2bf_rne(v0[3]);
    h[4] = f2bf_rne(v1[0]); h[5] = f2bf_rne(v1[1]);
    h[6] = f2bf_rne(v1[2]); h[7] = f2bf_rne(v1[3]);
    *(u16x8*)(dst + i) = h;
}

__global__ __launch_bounds__(256) void cvt_w_kernel(const float* __restrict__ w,
                                                    const int* __restrict__ eid,
                                                    u16* __restrict__ dst) {
    const float* src = w + (size_t)(*eid) * ((size_t)N_OUT * K_DIM);
    size_t i = ((size_t)blockIdx.x * 256 + threadIdx.x) * 8;
    f32x4 v0 = *(const f32x4*)(src + i);
    f32x4 v1 = *(const f32x4*)(src + i + 4);
    u16x8 h;
    h[0] = f2bf_rne(v0[0]); h[1] = f2bf_rne(v0[1]);
    h[2] = f2bf_rne(v0[2]); h[3] = f2bf_rne(v0[3]);
    h[4] = f2bf_rne(v1[0]); h[5] = f2bf_rne(v1[1]);
    h[6] = f2bf_rne(v1[2]); h[7] = f2bf_rne(v1[3]);
    *(u16x8*)(dst + i) = h;
}

// ---------------- 256x256 8-phase bf16 GEMM ----------------
// C[M,N] = A[M,K] * B[N,K]^T. BM=BN=256, BK=64, 8 waves (2Mx4N), 512 thr.
// LDS: lds[buf][mat][256*64] bf16, 128 KiB total. buf0 = even K-tiles,
// buf1 = odd (no toggling). Physical layout swizzled: 16B chunk at
// (row, slot) holds logical col16 = slot ^ (row&7). global_load_lds dest is
// linear; the per-lane global SOURCE address realizes the permutation.
//
// Phase schedule per iteration (tiles t=2i in buf0 P1-4, t+1 in buf1 P5-8),
// quadrant order (qm,qn) = (0,0),(1,0),(0,1),(1,1):
//   P1: ld aF0,bF01(buf0)          | stage b1(t+1)->buf1
//   P2: ld aF1(buf0)               |
//   P3: ld bF23(buf0)              | stage a0(t+2)->buf0
//   P4:                            | stage a1,b0(t+2)->buf0   vmcnt(6)
//   P5: ld aF0,bF01(buf1)          | stage b1(t+2)->buf0
//   P6: ld aF1(buf1)               |
//   P7: ld bF23(buf1)              | stage a0(t+3)->buf1
//   P8:                            | stage a1,b0(t+3)->buf1   vmcnt(6)
// Every staged region's last reader is >=1 barrier before the stage-issue;
// vmcnt(6) at P4/P8 completes exactly the half-tiles read in the next 4
// phases while keeping 3 half-tiles (6 loads) in flight.

__global__ __launch_bounds__(512, 2) void gemm256_8p(const u16* __restrict__ A,
                                                     const u16* __restrict__ B,
                                                     float* __restrict__ C) {
    __shared__ __align__(16) u16 lds[2][2][16384];

    const int tid  = threadIdx.x;
    const int wid  = tid >> 6;
    const int lane = tid & 63;
    const int wr = wid >> 2;      // 0..1  (M)
    const int wc = wid & 3;       // 0..3  (N)
    const int brow = blockIdx.y * 256;
    const int bcol = blockIdx.x * 256;

    // ---- staging source offsets (inverse-swizzled per-lane global addr) ----
    const int rsel = lane >> 3;                // 0..7
    const int slot = lane & 7;                 // 16B chunk slot within row
    const int scol = ((slot ^ rsel) << 3);     // logical col (elements)
    u32 aoff[2][2], boff[2][2];                // [half][call], elem offset @kt=0
#pragma unroll
    for (int h = 0; h < 2; ++h)
#pragma unroll
        for (int c = 0; c < 2; ++c) {
            const int row = h * 128 + wid * 8 + c * 64 + rsel;
            aoff[h][c] = (u32)(brow + row) * K_DIM + scol;
            boff[h][c] = (u32)(bcol + row) * K_DIM + scol;
        }

    // ---- fragment read bases (swizzled LDS addr) ----
    const int la = lane & 15, kb = lane >> 4, l7 = lane & 7;
    const int aB[2] = {(wr * 128 + la) * 64 + ((kb ^ l7) << 3),
                       (wr * 128 + la) * 64 + (((4 + kb) ^ l7) << 3)};
    const int bB[2] = {(wc * 64 + la) * 64 + ((kb ^ l7) << 3),
                       (wc * 64 + la) * 64 + (((4 + kb) ^ l7) << 3)};

    f32x4 acc[8][4] = {};
    bf16x8 aF0[4][2], aF1[4][2], bF[2][2];

#define STAGE_A(buf, h, kt) do { \
    async16(A + aoff[h][0] + (u32)(kt) * 64, &lds[buf][0][(h) * 8192 + wid * 512]); \
    async16(A + aoff[h][1] + (u32)(kt) * 64, &lds[buf][0][(h) * 8192 + wid * 512 + 4096]); \
} while (0)
#define STAGE_B(buf, h, kt) do { \
    async16(B + boff[h][0] + (u32)(kt) * 64, &lds[buf][1][(h) * 8192 + wid * 512]); \
    async16(B + boff[h][1] + (u32)(kt) * 64, &lds[buf][1][(h) * 8192 + wid * 512 + 4096]); \
} while (0)

#define LD_A0(buf) do { \
    _Pragma("unroll") for (int m = 0; m < 4; ++m) \
    _Pragma("unroll") for (int ks = 0; ks < 2; ++ks) \
        aF0[m][ks] = *(const bf16x8*)&lds[buf][0][aB[ks] + m * 1024]; \
} while (0)
#define LD_A1(buf) do { \
    _Pragma("unroll") for (int m = 0; m < 4; ++m) \
    _Pragma("unroll") for (int ks = 0; ks < 2; ++ks) \
        aF1[m][ks] = *(const bf16x8*)&lds[buf][0][aB[ks] + (m + 4) * 1024]; \
} while (0)
#define LD_B01(buf) do { \
    _Pragma("unroll") for (int n = 0; n < 2; ++n) \
    _Pragma("unroll") for (int ks = 0; ks < 2; ++ks) \
        bF[n][ks] = *(const bf16x8*)&lds[buf][1][bB[ks] + n * 1024]; \
} while (0)
#define LD_B23(buf) do { \
    _Pragma("unroll") for (int n = 0; n < 2; ++n) \
    _Pragma("unroll") for (int ks = 0; ks < 2; ++ks) \
        bF[n][ks] = *(const bf16x8*)&lds[buf][1][bB[ks] + (n + 2) * 1024]; \
} while (0)

#define MMQ(AA, QM, QN) do { \
    __builtin_amdgcn_s_setprio(1); \
    _Pragma("unroll") for (int m = 0; m < 4; ++m) \
    _Pragma("unroll") for (int n = 0; n < 2; ++n) \
    _Pragma("unroll") for (int ks = 0; ks < 2; ++ks) \
        acc[(QM) * 4 + m][(QN) * 2 + n] = __builtin_amdgcn_mfma_f32_16x16x32_bf16( \
            AA[m][ks], bF[n][ks], acc[(QM) * 4 + m][(QN) * 2 + n], 0, 0, 0); \
    __builtin_amdgcn_s_setprio(0); \
} while (0)

    // ---- prologue: tile0 full + tile1 {a0,a1,b0}; leave 6 loads in flight ----
    STAGE_A(0, 0, 0); STAGE_A(0, 1, 0); STAGE_B(0, 0, 0); STAGE_B(0, 1, 0);
    STAGE_A(1, 0, 1);
    STAGE_A(1, 1, 1); STAGE_B(1, 0, 1);
    VMCNT(6);
    __builtin_amdgcn_s_barrier();
    asm volatile("" ::: "memory");

#pragma unroll 1
    for (int it = 0; it < NT / 2; ++it) {
        const int t1 = 2 * it + 1;
        const int t2 = (2 * it + 2) & (NT - 1);   // wrap keeps tail loads in-bounds
        const int t3 = (2 * it + 3) & (NT - 1);
        // P1
        LD_A0(0); LD_B01(0);
        STAGE_B(1, 1, t1);
        bar(); MMQ(aF0, 0, 0); bar();
        // P2
        LD_A1(0);
        bar(); MMQ(aF1, 1, 0); bar();
        // P3
        LD_B23(0);
        STAGE_A(0, 0, t2);
        bar(); MMQ(aF0, 0, 1); bar();
        // P4
        STAGE_A(0, 1, t2); STAGE_B(0, 0, t2);
        bar(); MMQ(aF1, 1, 1);
        VMCNT(6); bar();
        // P5
        LD_A0(1); LD_B01(1);
        STAGE_B(0, 1, t2);
        bar(); MMQ(aF0, 0, 0); bar();
        // P6
        LD_A1(1);
        bar(); MMQ(aF1, 1, 0); bar();
        // P7
        LD_B23(1);
        STAGE_A(1, 0, t3);
        bar(); MMQ(aF0, 0, 1); bar();
        // P8
        STAGE_A(1, 1, t3); STAGE_B(1, 0, t3);
        bar(); MMQ(aF1, 1, 1);
        VMCNT(6); bar();
    }

    // ---- epilogue: D col = lane&15, row = (lane>>4)*4 + j ----
    asm volatile("" ::: "memory");
#pragma unroll
    for (int mi = 0; mi < 8; ++mi)
#pragma unroll
        for (int n = 0; n < 4; ++n) {
            float* cp = C + (size_t)(brow + wr * 128 + mi * 16 + kb * 4) * N_OUT
                          + (bcol + wc * 64 + n * 16 + la);
#pragma unroll
            for (int j = 0; j < 4; ++j)
                cp[(size_t)j * N_OUT] = acc[mi][n][j];
        }
}

// ---------------- fused-conversion fallback (no workspace) ----------------

__global__ __launch_bounds__(256) void gemm_fused(const float* __restrict__ Af,
                                                  const float* __restrict__ Wf,
                                                  const int* __restrict__ eid,
                                                  float* __restrict__ C) {
    const float* Bf = Wf + (size_t)(*eid) * ((size_t)N_OUT * K_DIM);

    __shared__ __align__(16) u16 As[2][4096];
    __shared__ __align__(16) u16 Bs[2][4096];

    const int tid  = threadIdx.x;
    const int wid  = tid >> 6;
    const int lane = tid & 63;
    const int brow = blockIdx.y * 128;
    const int bcol = blockIdx.x * 128;
    const int wr = wid >> 1, wc = wid & 1;

    f32x4 acc[4][4] = {};

    auto stage = [&](int buf, int kt) {
#pragma unroll
        for (int i = 0; i < 2; ++i) {
            const int l = tid + i * 256;
            const int g = l >> 6, c4 = (l >> 4) & 3, r = l & 15;
            {
                const size_t base = (size_t)(brow + g * 16 + r) * K_DIM + c4 * 8 + kt * 32;
                f32x4 v0 = *(const f32x4*)(Af + base);
                f32x4 v1 = *(const f32x4*)(Af + base + 4);
                u16x8 h;
                h[0] = f2bf_rne(v0[0]); h[1] = f2bf_rne(v0[1]);
                h[2] = f2bf_rne(v0[2]); h[3] = f2bf_rne(v0[3]);
                h[4] = f2bf_rne(v1[0]); h[5] = f2bf_rne(v1[1]);
                h[6] = f2bf_rne(v1[2]); h[7] = f2bf_rne(v1[3]);
                *(u16x8*)&As[buf][l * 8] = h;
            }
            {
                const size_t base = (size_t)(bcol + g * 16 + r) * K_DIM + c4 * 8 + kt * 32;
                f32x4 v0 = *(const f32x4*)(Bf + base);
                f32x4 v1 = *(const f32x4*)(Bf + base + 4);
                u16x8 h;
                h[0] = f2bf_rne(v0[0]); h[1] = f2bf_rne(v0[1]);
                h[2] = f2bf_rne(v0[2]); h[3] = f2bf_rne(v0[3]);
                h[4] = f2bf_rne(v1[0]); h[5] = f2bf_rne(v1[1]);
                h[6] = f2bf_rne(v1[2]); h[7] = f2bf_rne(v1[3]);
                *(u16x8*)&Bs[buf][l * 8] = h;
            }
        }
    };

    auto compute = [&](int buf) {
        bf16x8 a[4], b[4];
#pragma unroll
        for (int m = 0; m < 4; ++m)
            a[m] = *(const bf16x8*)&As[buf][(wr * 4 + m) * 512 + lane * 8];
#pragma unroll
        for (int n = 0; n < 4; ++n)
            b[n] = *(const bf16x8*)&Bs[buf][(wc * 4 + n) * 512 + lane * 8];
#pragma unroll
        for (int m = 0; m < 4; ++m)
#pragma unroll
            for (int n = 0; n < 4; ++n)
                acc[m][n] = __builtin_amdgcn_mfma_f32_16x16x32_bf16(a[m], b[n], acc[m][n], 0, 0, 0);
    };

    stage(0, 0);
    __syncthreads();
    int cur = 0;
#pragma unroll 1
    for (int kt = 0; kt < (K_DIM / 32) - 1; ++kt) {
        stage(cur ^ 1, kt + 1);
        compute(cur);
        __syncthreads();
        cur ^= 1;
    }
    compute(cur);

    const int r0 = (lane >> 4) * 4;
    const int cn = lane & 15;
#pragma unroll
    for (int m = 0; m < 4; ++m)
#pragma unroll
        for (int n = 0; n < 4; ++n) {
            float* cp = C + (size_t)(brow + wr * 64 + m * 16 + r0) * N_OUT
                          + (bcol + wc * 64 + n * 16 + cn);
#pragma unroll
            for (int j = 0; j < 4; ++j)
                cp[(size_t)j * N_OUT] = acc[m][n][j];
        }
}

// ---------------- launch ----------------

extern "C" void kernel_launch(void* const* d_in, const int* in_sizes, int n_in,
                              void* d_out, int out_size, void* d_ws, size_t ws_size,
                              hipStream_t stream) {
    const float* state = (const float*)d_in[0];
    const float* w     = (const float*)d_in[1];
    const int*   eid   = (const int*)d_in[2];
    float*       out   = (float*)d_out;

    const size_t nA = (size_t)M_TOK * K_DIM;   // 16,777,216
    const size_t nB = (size_t)N_OUT * K_DIM;   // 58,720,256
    const size_t need = (nA + nB) * sizeof(u16);

    if (d_ws != nullptr && ws_size >= need) {
        u16* a16 = (u16*)d_ws;
        u16* b16 = a16 + nA;
        cvt_state_kernel<<<(unsigned)(nA / 2048), 256, 0, stream>>>(state, a16);
        cvt_w_kernel<<<(unsigned)(nB / 2048), 256, 0, stream>>>(w, eid, b16);
        dim3 grid(N_OUT / 256, M_TOK / 256);
        gemm256_8p<<<grid, 512, 0, stream>>>(a16, b16, out);
    } else {
        dim3 grid(N_OUT / 128, M_TOK / 128);
        gemm_fused<<<grid, 256, 0, stream>>>(state, w, eid, out);
    }
}